// Round 6
// baseline (68.963 us; speedup 1.0000x reference)
//
#include <hip/hip_runtime.h>
#include <math.h>

// Problem constants (from reference)
#define XS 540
#define YS 540
#define NB 4            // batch
#define NBOX 64
#define TILE 36         // 36x36 cells per block
#define TPX 15          // 540 / 36
#define NTILE (TPX * TPX)       // 225
#define QPT (36 * 9)            // 324 float4 groups per tile
#define XS4 (XS / 4)            // 135 float4 per row

// Structure note (r1-r4): ALL in-kernel cross-block handoffs lose to a second
// launch on this chip/harness (threadfence +14us, contended RMW +12..21us,
// zero-RMW flag-poll +5us). Two kernels, graph-captured gap, stays.
//
// r6 experiment (model discriminator): coalesced LDS box staging + setprio(1)
// on the wave-0 prologue. Bit-identical math; targets the prologue's
// uncoalesced global chain. If dur_us doesn't move, our kernels are hidden
// under the harness fill+reset storm -> harness-bound roofline.
//
// d_ws layout: float part[NB][NTILE][4] = { s1, s2, cnt, pad }.
// Every slot fully written by its owning block -> no zero-init needed.

__global__ __launch_bounds__(256) void hmdl_main(
    const float* __restrict__ logits,   // [4,1,540,540]
    const float* __restrict__ boxes,    // [4,64,7]
    const float* __restrict__ hmaps,    // [4,1,540,540]
    float4* __restrict__ part)          // [NB*NTILE]
{
    __shared__ float s_braw[NBOX * 7];  // raw boxes[b] floats (448)
    __shared__ float s_cx[NBOX], s_cy[NBOX], s_c[NBOX], s_s[NBOX];
    __shared__ float s_hw[NBOX], s_hl[NBOX], s_hv[NBOX];
    __shared__ int   s_sel[NBOX];
    __shared__ int   s_nsel;
    __shared__ float s_red[3][4];

    const int b    = blockIdx.y;
    const int tile = blockIdx.x;
    const int tx0  = (tile % TPX) * TILE;
    const int ty0  = (tile / TPX) * TILE;
    const int tid  = threadIdx.x;

    // ---- wave0: issue the boxes panel loads FIRST (oldest in the vmcnt queue,
    //      coalesced: 112 float4 = all 448 floats of boxes[b]) ----
    const float4* bx4 = (const float4*)(boxes + b * (NBOX * 7));
    float4 br0 = make_float4(0.f, 0.f, 0.f, 0.f), br1 = br0;
    if (tid < 64) {
        br0 = bx4[tid];
        if (tid < 48) br1 = bx4[64 + tid];
    }

    // ---- all threads: issue tile loads next (latency drains under prologue) ----
    const float4* lg4 = (const float4*)logits;
    const float4* hm4 = (const float4*)hmaps;

    const int  q0   = tid;                       // always < 324
    const int  row0 = q0 / 9;
    const int  c40  = q0 - row0 * 9;
    const int  idx0 = (b * YS + ty0 + row0) * XS4 + (tx0 >> 2) + c40;
    const float4 xv0 = lg4[idx0];
    const float4 hm0 = hm4[idx0];

    const int  q1   = tid + 256;
    const bool has1 = (q1 < QPT);
    const int  row1 = q1 / 9;
    const int  c41  = q1 - row1 * 9;
    const int  idx1 = has1 ? ((b * YS + ty0 + row1) * XS4 + (tx0 >> 2) + c41) : idx0;
    const float4 xv1 = lg4[idx1];                // dup of idx0 when !has1: L1 hit
    const float4 hm1 = hm4[idx1];

    // ---- wave0 prologue: stage boxes to LDS, compute constants, cull ----
    if (tid < 64) {
        __builtin_amdgcn_s_setprio(1);   // critical path: favor this wave
        ((float4*)s_braw)[tid] = br0;
        if (tid < 48) ((float4*)s_braw)[64 + tid] = br1;
        // same-wave cross-lane LDS visibility: drain the ds_writes
        asm volatile("s_waitcnt lgkmcnt(0)" ::: "memory");

        const float* bx = s_braw + tid * 7;      // stride 7: coprime w/ 32 banks
        float b0 = bx[0], b1 = bx[1], b3 = bx[3], b4 = bx[4], b5 = bx[5], b6 = bx[6];
        float cx = (b0 - (-54.0f)) / 0.2f;
        float cy = (b1 - (-54.0f)) / 0.2f;
        float hw = (b3 / 0.2f) * 0.5f;
        float hl = (b4 / 0.2f) * 0.5f;
        float c  = cosf(-b6);
        float s  = sinf(-b6);
        float hv = b5 / 5.0f;   // h / (PC_RANGE[5] + 2.0) = h / 5
        s_cx[tid] = cx; s_cy[tid] = cy; s_c[tid] = c; s_s[tid] = s;
        s_hw[tid] = hw; s_hl[tid] = hl; s_hv[tid] = hv;

        // exact AABB of the rotated rect
        float ex = fabsf(hw * c) + fabsf(hl * s);
        float ey = fabsf(hw * s) + fabsf(hl * c);
        bool hit = (cx + ex >= (float)tx0) && (cx - ex <= (float)(tx0 + TILE - 1)) &&
                   (cy + ey >= (float)ty0) && (cy - ey <= (float)(ty0 + TILE - 1));
        unsigned long long m = __ballot(hit);
        if (hit) {
            int pos = __popcll(m & ((1ull << tid) - 1ull));
            s_sel[pos] = tid;   // ascending j order preserved -> "last box wins" intact
        }
        if (tid == 0) s_nsel = __popcll(m);
        __builtin_amdgcn_s_setprio(0);
    }
    __syncthreads();
    const int nsel = s_nsel;

    float a1 = 0.0f, a2 = 0.0f, ac = 0.0f;

    auto process = [&](int row, int c4, float4 xv, float4 hm) {
        const float xg = (float)(tx0 + c4 * 4);
        const float yg = (float)(ty0 + row);

        // rasterize 4 consecutive cells: last covering box wins; incremental lx/ly
        float g0 = 0.0f, g1 = 0.0f, g2 = 0.0f, g3 = 0.0f;
        for (int k = 0; k < nsel; ++k) {
            const int j = s_sel[k];
            const float cj = s_c[j], sj = s_s[j];
            const float hw = s_hw[j], hl = s_hl[j], hv = s_hv[j];
            const float dx = xg - s_cx[j];
            const float dy = yg - s_cy[j];
            float lx = dx * cj - dy * sj;
            float ly = dx * sj + dy * cj;
            if (fabsf(lx) <= hw && fabsf(ly) <= hl) g0 = hv;
            lx += cj; ly += sj;
            if (fabsf(lx) <= hw && fabsf(ly) <= hl) g1 = hv;
            lx += cj; ly += sj;
            if (fabsf(lx) <= hw && fabsf(ly) <= hl) g2 = hv;
            lx += cj; ly += sj;
            if (fabsf(lx) <= hw && fabsf(ly) <= hl) g3 = hv;
        }

        const float gts[4] = { g0, g1, g2, g3 };
        const float xvs[4] = { xv.x, xv.y, xv.z, xv.w };
        const float hms[4] = { hm.x, hm.y, hm.z, hm.w };

        #pragma unroll
        for (int m = 0; m < 4; ++m) {
            const float gt = gts[m];
            const float x_ = xvs[m];
            const bool  pos = gt > 0.0f;                 // neg == !pos
            const float weight = pos ? 5.0f : 0.1f;
            const bool  point = hms[m] > 0.0f;
            const float valid = (pos || point) ? 1.0f : 0.0f;

            // t = e^{-|x|};  sigmoid(x) = x>=0 ? 1/(1+t) : t/(1+t)
            const float t  = __expf(-fabsf(x_));
            const float bce = fmaxf(x_, 0.0f) - x_ * gt + __logf(1.0f + t);
            const float r  = 1.0f / (1.0f + t);
            const float p  = (x_ >= 0.0f) ? r : (t * r);
            const float pt = p * gt + (1.0f - p) * (1.0f - gt);
            const float aw = 0.25f * gt + 0.75f * (1.0f - gt);
            const float om = 1.0f - pt;
            const float fw = om * om * aw * weight;

            a1 += weight * bce * valid;
            a2 += fw * bce * valid;
            ac += valid;
        }
    };

    process(row0, c40, xv0, hm0);      // same per-thread order as the r0 q-loop
    if (has1) process(row1, c41, xv1, hm1);

    // ---- block reduction: wave64 shuffle + cross-wave LDS ----
    for (int off = 32; off > 0; off >>= 1) {
        a1 += __shfl_down(a1, off);
        a2 += __shfl_down(a2, off);
        ac += __shfl_down(ac, off);
    }
    const int wave = tid >> 6;
    if ((tid & 63) == 0) { s_red[0][wave] = a1; s_red[1][wave] = a2; s_red[2][wave] = ac; }
    __syncthreads();
    if (tid == 0) {
        float t1 = s_red[0][0] + s_red[0][1] + s_red[0][2] + s_red[0][3];
        float t2 = s_red[1][0] + s_red[1][1] + s_red[1][2] + s_red[1][3];
        float t3 = s_red[2][0] + s_red[2][1] + s_red[2][2] + s_red[2][3];
        part[b * NTILE + tile] = make_float4(t1, t2, t3, 0.0f);
    }
}

// One block, 256 threads: wave w reduces sample w's 225 tile-partials.
__global__ __launch_bounds__(256) void hmdl_finalize(
    const float4* __restrict__ part, float* __restrict__ out)
{
    __shared__ float s_comb[NB];
    __shared__ float s_has[NB];

    const int tid  = threadIdx.x;
    const int b    = tid >> 6;
    const int lane = tid & 63;

    double d1 = 0.0, d2 = 0.0, d3 = 0.0;
    for (int t = lane; t < NTILE; t += 64) {
        float4 v = part[b * NTILE + t];
        d1 += (double)v.x; d2 += (double)v.y; d3 += (double)v.z;
    }
    for (int off = 32; off > 0; off >>= 1) {
        d1 += __shfl_down(d1, off);
        d2 += __shfl_down(d2, off);
        d3 += __shfl_down(d3, off);
    }
    if (lane == 0) {
        float cnt   = (float)d3;
        float denom = fmaxf(cnt, 1.0f);
        float bl = (float)d1 / denom;
        float fl = (float)d2 / denom;
        bool has = cnt > 0.0f;
        s_comb[b] = has ? (0.5f * bl + 0.5f * fl) : 0.0f;
        s_has[b]  = has ? 1.0f : 0.0f;
    }
    __syncthreads();
    if (tid == 0) {
        float total = s_comb[0] + s_comb[1] + s_comb[2] + s_comb[3];
        float ns    = s_has[0] + s_has[1] + s_has[2] + s_has[3];
        out[0] = (ns > 0.0f) ? (total / fmaxf(ns, 1.0f)) : total;
    }
}

extern "C" void kernel_launch(void* const* d_in, const int* in_sizes, int n_in,
                              void* d_out, int out_size, void* d_ws, size_t ws_size,
                              hipStream_t stream) {
    const float* logits = (const float*)d_in[0];
    const float* boxes  = (const float*)d_in[1];
    const float* hmaps  = (const float*)d_in[2];
    float* out = (float*)d_out;
    float4* part = (float4*)d_ws;

    dim3 grid(NTILE, NB);
    hmdl_main<<<grid, 256, 0, stream>>>(logits, boxes, hmaps, part);
    hmdl_finalize<<<1, 256, 0, stream>>>(part, out);
}